// Round 5
// baseline (1073.510 us; speedup 1.0000x reference)
//
#include <hip/hip_runtime.h>
#include <hip/hip_bf16.h>
#include <hip/hip_cooperative_groups.h>

namespace cg = cooperative_groups;

#define NB 16
#define NVEC 2048
#define NDIM 32
#define NW 4
#define NHID 128
#define NCLASS 10
#define USIZE (129 * 32)   // 4128: U rows 0..127 = fw2@V, row 128 = fb2^T@V
#define NBLK 512
#define MS_FB 16           // m-splits for fallback k_U

__device__ __forceinline__ float gelu_exact(float x) {
    return 0.5f * x * (1.0f + erff(x * 0.70710678118654752f));
}
// tanh-approx GELU; max abs deviation ~3e-3, threshold is 0.159.
__device__ __forceinline__ float gelu_fast(float x) {
    float t = 1.5957691216057308f * x * (1.0f + 0.044715f * x * x);
    return x / (1.0f + __expf(-t));
}

// ===========================================================================
// Cooperative mega-kernel. smem = 13600 floats = 54.4 KB (< 64 KB per-block
// cap, 2 blocks/CU from 160 KB pool).
//  PU: Vs[64*32]=2048 | fwt[128*67]=8576                    (10624)
//  PA: Us[4128] | w1s[4096] | xt[32*36]=1152 | hs[32*132]=4224  (13600)
//  PF: red[2560]
__global__ __launch_bounds__(256, 2) void k_mega(
    const int* __restrict__ data, const float* __restrict__ emb,
    const float* __restrict__ fw1, const float* __restrict__ fb1,
    const float* __restrict__ fw2, const float* __restrict__ fb2,
    const float* __restrict__ Wf, const float* __restrict__ bf,
    float* __restrict__ out,
    float* __restrict__ X, float* __restrict__ VA, float* __restrict__ VB,
    float* __restrict__ UA, float* __restrict__ UB) {
    cg::grid_group grid = cg::this_grid();
    __shared__ float smem[13600];
    int blk = blockIdx.x, tid = threadIdx.x;

    // ---- P0: embed gather + zero both U buffers + out = bias ----------------
    {
        int base = blk * 2048;
#pragma unroll
        for (int j = 0; j < 8; ++j) {
            int gid = base + tid + j * 256;
            int row = gid >> 5, d = gid & 31;
            X[gid] = emb[data[row] * NDIM + d];
        }
        if (tid < 129) {                       // 512*129 = 66048 exactly
            UA[blk * 129 + tid] = 0.f;
            UB[blk * 129 + tid] = 0.f;
        }
        if (blk == 0 && tid < NB * NCLASS) out[tid] = bf[tid % NCLASS];
    }
    grid.sync();

    const float* Vcur = X;
    float* Vnext = VA;
    float* Ucur = UA;
    float* Uother = UB;
    for (int l = NW - 1; l >= 0; --l) {
        const float* fw2l = fw2 + l * NHID * NVEC;
        const float* fb2l = fb2 + l * NVEC;

        // -- PU: partial U over 64 m's, atomicAdd into Ucur ------------------
        {
            int b = blk & 15, ms = blk >> 4;   // 32 m-splits of 64
            int m0 = ms * 64;
            float* Vs = smem;                  // [mm][d] 64x32
            float* fwt = smem + 2048;          // [k][mm] 128x67 (2-way free)
            const float* Vb = Vcur + (b * NVEC + m0) * NDIM;
#pragma unroll
            for (int j = 0; j < 2; ++j) {
                int i4 = tid + j * 256;
                ((float4*)Vs)[i4] = ((const float4*)Vb)[i4];
            }
#pragma unroll
            for (int j = 0; j < 8; ++j) {      // 128x64 tile
                int i4 = tid + j * 256;
                int k = i4 >> 4, mm4 = (i4 & 15) * 4;
                float4 w = *(const float4*)&fw2l[k * NVEC + m0 + mm4];
                float* dst = &fwt[k * 67 + mm4];
                dst[0] = w.x; dst[1] = w.y; dst[2] = w.z; dst[3] = w.w;
            }
            __syncthreads();

            int k1 = tid & 63, k2 = k1 + 64, d0 = (tid >> 6) * 8;
            float acc1[8], acc2[8];
#pragma unroll
            for (int j = 0; j < 8; ++j) { acc1[j] = 0.f; acc2[j] = 0.f; }
#pragma unroll 4
            for (int mm = 0; mm < 64; ++mm) {
                float w1v = fwt[k1 * 67 + mm];
                float w2v = fwt[k2 * 67 + mm];
                const float* vr = &Vs[mm * 32 + d0];
                float4 va = *(const float4*)vr;
                float4 vb4 = *(const float4*)(vr + 4);
                float vv[8] = {va.x, va.y, va.z, va.w, vb4.x, vb4.y, vb4.z, vb4.w};
#pragma unroll
                for (int j = 0; j < 8; ++j) {
                    acc1[j] += w1v * vv[j];
                    acc2[j] += w2v * vv[j];
                }
            }
            float* Ub = Ucur + b * USIZE;
#pragma unroll
            for (int j = 0; j < 8; ++j) atomicAdd(&Ub[k1 * 32 + d0 + j], acc1[j]);
#pragma unroll
            for (int j = 0; j < 8; ++j) atomicAdd(&Ub[k2 * 32 + d0 + j], acc2[j]);
            if (tid < 32) {                    // bias row
                float ca = 0.f;
#pragma unroll 8
                for (int mm = 0; mm < 64; ++mm) ca += fb2l[m0 + mm] * Vs[mm * 32 + tid];
                atomicAdd(&Ub[NHID * 32 + tid], ca);
            }
        }
        grid.sync();

        // -- PA: two 32-row subtiles: h=gelu(X@fw1+fb1); V=h@U+U[128] --------
        {
            int b = blk & 15, ng = blk >> 4;
            float* Us = smem;                  // 4128
            float* w1s = smem + 4128;          // [d][k]
            float* xt = smem + 8224;           // [d][r] 32x36
            float* hs = smem + 9376;           // [r][k] 32x132
            const float* fw1l = fw1 + l * NDIM * NHID;
            const float* fb1l = fb1 + l * NHID;

            {
                const float4* Ug = (const float4*)(Ucur + b * USIZE);
                for (int i4 = tid; i4 < 1032; i4 += 256) ((float4*)Us)[i4] = Ug[i4];
            }
#pragma unroll
            for (int j = 0; j < 4; ++j) {
                int i4 = tid + j * 256;
                ((float4*)w1s)[i4] = ((const float4*)fw1l)[i4];
            }

#pragma unroll
            for (int t = 0; t < 2; ++t) {
                int n0 = (ng * 2 + t) * 32;
                {   // stage X transposed -> xt[d][r], 256 float4s
                    const float4* Xg = (const float4*)(X + (b * NVEC + n0) * NDIM);
                    int i4 = tid;
                    float4 v = Xg[i4];
                    int n = i4 >> 3, d4 = (i4 & 7) * 4;
                    xt[(d4 + 0) * 36 + n] = v.x;
                    xt[(d4 + 1) * 36 + n] = v.y;
                    xt[(d4 + 2) * 36 + n] = v.z;
                    xt[(d4 + 3) * 36 + n] = v.w;
                }
                __syncthreads();

                {   // h: thread tile 2 rows x 8 k
                    int kg = tid & 15, rg = tid >> 4;
                    int k0 = kg * 8, r0 = rg * 2;
                    float acc[2][8];
#pragma unroll
                    for (int j = 0; j < 8; ++j) {
                        float bv = fb1l[k0 + j];
                        acc[0][j] = bv; acc[1][j] = bv;
                    }
#pragma unroll 8
                    for (int d = 0; d < NDIM; ++d) {
                        float2 xv = *(const float2*)&xt[d * 36 + r0];
                        float4 wa = *(const float4*)&w1s[d * NHID + k0];
                        float4 wb = *(const float4*)&w1s[d * NHID + k0 + 4];
                        float wk[8] = {wa.x, wa.y, wa.z, wa.w, wb.x, wb.y, wb.z, wb.w};
#pragma unroll
                        for (int j = 0; j < 8; ++j) {
                            acc[0][j] += xv.x * wk[j];
                            acc[1][j] += xv.y * wk[j];
                        }
                    }
#pragma unroll
                    for (int r = 0; r < 2; ++r) {
                        float4 o0, o1;
                        o0.x = gelu_fast(acc[r][0]); o0.y = gelu_fast(acc[r][1]);
                        o0.z = gelu_fast(acc[r][2]); o0.w = gelu_fast(acc[r][3]);
                        o1.x = gelu_fast(acc[r][4]); o1.y = gelu_fast(acc[r][5]);
                        o1.z = gelu_fast(acc[r][6]); o1.w = gelu_fast(acc[r][7]);
                        *(float4*)&hs[(r0 + r) * 132 + k0] = o0;
                        *(float4*)&hs[(r0 + r) * 132 + k0 + 4] = o1;
                    }
                }
                __syncthreads();

                {   // apply: 1 row x 4 d per thread over K=128
                    int d0 = (tid & 7) * 4, r0 = tid >> 3;
                    float4 a0 = *(const float4*)&Us[NHID * 32 + d0];
#pragma unroll 8
                    for (int k = 0; k < NHID; k += 4) {
                        float4 h0 = *(const float4*)&hs[r0 * 132 + k];
                        float4 u0 = *(const float4*)&Us[(k + 0) * 32 + d0];
                        float4 u1 = *(const float4*)&Us[(k + 1) * 32 + d0];
                        float4 u2 = *(const float4*)&Us[(k + 2) * 32 + d0];
                        float4 u3 = *(const float4*)&Us[(k + 3) * 32 + d0];
                        a0.x += h0.x * u0.x + h0.y * u1.x + h0.z * u2.x + h0.w * u3.x;
                        a0.y += h0.x * u0.y + h0.y * u1.y + h0.z * u2.y + h0.w * u3.y;
                        a0.z += h0.x * u0.z + h0.y * u1.z + h0.z * u2.z + h0.w * u3.z;
                        a0.w += h0.x * u0.w + h0.y * u1.w + h0.z * u2.w + h0.w * u3.w;
                    }
                    *(float4*)&Vnext[(b * NVEC + n0 + r0) * NDIM + d0] = a0;
                }
                __syncthreads();               // hs reused next subtile
            }
            if (tid < 129) Uother[blk * 129 + tid] = 0.f;
        }
        grid.sync();

        Vcur = Vnext;
        Vnext = (Vnext == VA) ? VB : VA;
        float* tu = Ucur; Ucur = Uother; Uother = tu;
    }

    // ---- PF: out[b,c] += sum_j V[b,j]*Wf[j,c] -------------------------------
    {
        int b = blk & 15, chunk = blk >> 4;
        const float* Vb = Vcur + b * (NVEC * NDIM);
        int j0 = chunk * 2048;
        float acc[NCLASS];
#pragma unroll
        for (int c = 0; c < NCLASS; ++c) acc[c] = 0.f;
#pragma unroll
        for (int jj = 0; jj < 8; ++jj) {
            int j = j0 + tid + jj * 256;
            float v = Vb[j];
            const float* wr = Wf + (size_t)j * NCLASS;
#pragma unroll
            for (int c = 0; c < NCLASS; ++c) acc[c] += v * wr[c];
        }
        float* red = smem;
#pragma unroll
        for (int c = 0; c < NCLASS; ++c) red[tid * NCLASS + c] = acc[c];
        __syncthreads();
        for (int off = 128; off >= 1; off >>= 1) {
            if (tid < off) {
#pragma unroll
                for (int c = 0; c < NCLASS; ++c)
                    red[tid * NCLASS + c] += red[(tid + off) * NCLASS + c];
            }
            __syncthreads();
        }
        if (tid < NCLASS) atomicAdd(&out[b * NCLASS + tid], red[tid]);
    }
}

// ===========================================================================
// Fallback path: R3's proven kernels (235 us).
__global__ __launch_bounds__(256) void k_embed(const int* __restrict__ data,
                                               const float* __restrict__ emb,
                                               float* __restrict__ X) {
    int gid = blockIdx.x * 256 + threadIdx.x;
    int row = gid >> 5, d = gid & 31;
    X[gid] = emb[data[row] * NDIM + d];
}

__global__ __launch_bounds__(256) void k_H(const float* __restrict__ X,
                                           const float* __restrict__ fw1,
                                           const float* __restrict__ fb1,
                                           float* __restrict__ H) {
    __shared__ float w1s[NDIM * NHID];
    __shared__ float xt[NDIM][68];
    int n0 = blockIdx.x * 64, b = blockIdx.y, l = blockIdx.z;
    int tid = threadIdx.x;
    const float* w1 = fw1 + l * NDIM * NHID;
    for (int i = tid; i < NDIM * NHID; i += 256) w1s[i] = w1[i];
    const float* Xb = X + (b * NVEC + n0) * NDIM;
#pragma unroll
    for (int j = 0; j < 8; ++j) {
        int i = tid + j * 256;
        xt[i & 31][i >> 5] = Xb[i];
    }
    __syncthreads();
    int kg = tid & 15, rg = tid >> 4;
    int k0 = kg * 8, r0 = rg * 4;
    const float* fb = fb1 + l * NHID;
    float acc[4][8];
#pragma unroll
    for (int j = 0; j < 8; ++j) {
        float bv = fb[k0 + j];
#pragma unroll
        for (int r = 0; r < 4; ++r) acc[r][j] = bv;
    }
#pragma unroll 8
    for (int d = 0; d < NDIM; ++d) {
        float4 xv = *(const float4*)&xt[d][r0];
        float4 wa = *(const float4*)&w1s[d * NHID + k0];
        float4 wb = *(const float4*)&w1s[d * NHID + k0 + 4];
        float xr[4] = {xv.x, xv.y, xv.z, xv.w};
        float wk[8] = {wa.x, wa.y, wa.z, wa.w, wb.x, wb.y, wb.z, wb.w};
#pragma unroll
        for (int r = 0; r < 4; ++r)
#pragma unroll
            for (int j = 0; j < 8; ++j) acc[r][j] += xr[r] * wk[j];
    }
    float* hb = H + (((size_t)l * NB + b) * NVEC + n0) * NHID;
#pragma unroll
    for (int r = 0; r < 4; ++r) {
        float4 o0, o1;
        o0.x = gelu_exact(acc[r][0]); o0.y = gelu_exact(acc[r][1]);
        o0.z = gelu_exact(acc[r][2]); o0.w = gelu_exact(acc[r][3]);
        o1.x = gelu_exact(acc[r][4]); o1.y = gelu_exact(acc[r][5]);
        o1.z = gelu_exact(acc[r][6]); o1.w = gelu_exact(acc[r][7]);
        *(float4*)&hb[(r0 + r) * NHID + k0] = o0;
        *(float4*)&hb[(r0 + r) * NHID + k0 + 4] = o1;
    }
}

__global__ __launch_bounds__(256) void k_U(const float* __restrict__ V,
                                           const float* __restrict__ fw2,
                                           const float* __restrict__ fb2,
                                           float* __restrict__ Upart) {
    __shared__ float Vs[128 * 32];
    __shared__ float fw2s[128][33];
    __shared__ float cred[4][33];
    int ms = blockIdx.x, b = blockIdx.y;
    int tid = threadIdx.x;
    int m0 = ms * 128;
    const float* Vb = V + (b * NVEC + m0) * NDIM;
#pragma unroll
    for (int j = 0; j < 4; ++j) {
        int i4 = tid + j * 256;
        ((float4*)Vs)[i4] = ((const float4*)Vb)[i4];
    }
    int k1 = tid & 63, k2 = k1 + 64, d0 = (tid >> 6) * 8;
    float acc1[8], acc2[8];
#pragma unroll
    for (int j = 0; j < 8; ++j) { acc1[j] = 0.f; acc2[j] = 0.f; }
    for (int s = 0; s < 4; ++s) {
        __syncthreads();
        int moff = m0 + s * 32;
#pragma unroll
        for (int j = 0; j < 16; ++j) {
            int i = tid + j * 256;
            int kk = i >> 5, mm = i & 31;
            fw2s[kk][mm] = fw2[kk * NVEC + moff + mm];
        }
        __syncthreads();
#pragma unroll 8
        for (int mm = 0; mm < 32; ++mm) {
            float w1v = fw2s[k1][mm];
            float w2v = fw2s[k2][mm];
            const float* vrow = &Vs[(s * 32 + mm) * 32 + d0];
            float4 va = *(const float4*)vrow;
            float4 vb4 = *(const float4*)(vrow + 4);
            float vv[8] = {va.x, va.y, va.z, va.w, vb4.x, vb4.y, vb4.z, vb4.w};
#pragma unroll
            for (int j = 0; j < 8; ++j) {
                acc1[j] += w1v * vv[j];
                acc2[j] += w2v * vv[j];
            }
        }
    }
    float* Up = Upart + ((size_t)ms * NB + b) * USIZE;
    *(float4*)&Up[k1 * 32 + d0]     = make_float4(acc1[0], acc1[1], acc1[2], acc1[3]);
    *(float4*)&Up[k1 * 32 + d0 + 4] = make_float4(acc1[4], acc1[5], acc1[6], acc1[7]);
    *(float4*)&Up[k2 * 32 + d0]     = make_float4(acc2[0], acc2[1], acc2[2], acc2[3]);
    *(float4*)&Up[k2 * 32 + d0 + 4] = make_float4(acc2[4], acc2[5], acc2[6], acc2[7]);
    if (tid < 128) {
        int d = tid & 31, seg = tid >> 5;
        float ca = 0.f;
#pragma unroll 8
        for (int mm = seg * 32; mm < seg * 32 + 32; ++mm)
            ca += fb2[m0 + mm] * Vs[mm * 32 + d];
        cred[seg][d] = ca;
    }
    __syncthreads();
    if (tid < 32)
        Up[128 * 32 + tid] = cred[0][tid] + cred[1][tid] + cred[2][tid] + cred[3][tid];
}

__global__ __launch_bounds__(256) void k_apply(const float* __restrict__ Hl,
                                               const float* __restrict__ Upart,
                                               float* __restrict__ Vout) {
    __shared__ float UsF[USIZE];
    __shared__ float hs[64][132];
    int n0 = blockIdx.x * 64, b = blockIdx.y;
    int tid = threadIdx.x;
    for (int i = tid; i < USIZE; i += 256) {
        float s = 0.f;
#pragma unroll
        for (int msx = 0; msx < MS_FB; ++msx)
            s += Upart[((size_t)msx * NB + b) * USIZE + i];
        UsF[i] = s;
    }
    const float* hb = Hl + ((size_t)b * NVEC + n0) * NHID;
#pragma unroll
    for (int j = 0; j < 8; ++j) {
        int i4 = tid + j * 256;
        float4 v = ((const float4*)hb)[i4];
        int row = i4 >> 5, c4 = (i4 & 31) * 4;
        *(float4*)&hs[row][c4] = v;
    }
    __syncthreads();
    int d0 = (tid & 7) * 4, r0 = (tid >> 3) * 2;
    float4 cb = *(const float4*)&UsF[128 * 32 + d0];
    float4 a0 = cb, a1 = cb;
#pragma unroll 8
    for (int k = 0; k < NHID; k += 4) {
        float4 h0 = *(const float4*)&hs[r0][k];
        float4 h1 = *(const float4*)&hs[r0 + 1][k];
        float4 u0 = *(const float4*)&UsF[(k + 0) * 32 + d0];
        float4 u1 = *(const float4*)&UsF[(k + 1) * 32 + d0];
        float4 u2 = *(const float4*)&UsF[(k + 2) * 32 + d0];
        float4 u3 = *(const float4*)&UsF[(k + 3) * 32 + d0];
        a0.x += h0.x * u0.x + h0.y * u1.x + h0.z * u2.x + h0.w * u3.x;
        a0.y += h0.x * u0.y + h0.y * u1.y + h0.z * u2.y + h0.w * u3.y;
        a0.z += h0.x * u0.z + h0.y * u1.z + h0.z * u2.z + h0.w * u3.z;
        a0.w += h0.x * u0.w + h0.y * u1.w + h0.z * u2.w + h0.w * u3.w;
        a1.x += h1.x * u0.x + h1.y * u1.x + h1.z * u2.x + h1.w * u3.x;
        a1.y += h1.x * u0.y + h1.y * u1.y + h1.z * u2.y + h1.w * u3.y;
        a1.z += h1.x * u0.z + h1.y * u1.z + h1.z * u2.z + h1.w * u3.z;
        a1.w += h1.x * u0.w + h1.y * u1.w + h1.z * u2.w + h1.w * u3.w;
    }
    float* vo = Vout + ((size_t)b * NVEC + n0 + r0) * NDIM + d0;
    *(float4*)vo = a0;
    *(float4*)(vo + NDIM) = a1;
}

__global__ void k_bias_out(const float* __restrict__ bf, float* __restrict__ out) {
    int t = threadIdx.x;
    if (t < NB * NCLASS) out[t] = bf[t % NCLASS];
}

__global__ __launch_bounds__(256) void k_final(const float* __restrict__ V,
                                               const float* __restrict__ Wf,
                                               float* __restrict__ out) {
    int b = blockIdx.x, chunk = blockIdx.y;
    int tid = threadIdx.x;
    float acc[NCLASS];
#pragma unroll
    for (int c = 0; c < NCLASS; ++c) acc[c] = 0.f;
    const float* Vb = V + b * (NVEC * NDIM);
    int j0 = chunk * 2048;
    for (int j = j0 + tid; j < j0 + 2048; j += 256) {
        float v = Vb[j];
        const float* wr = Wf + (size_t)j * NCLASS;
#pragma unroll
        for (int c = 0; c < NCLASS; ++c) acc[c] += v * wr[c];
    }
    __shared__ float red[256][NCLASS];
#pragma unroll
    for (int c = 0; c < NCLASS; ++c) red[tid][c] = acc[c];
    __syncthreads();
    for (int off = 128; off >= 1; off >>= 1) {
        if (tid < off) {
#pragma unroll
            for (int c = 0; c < NCLASS; ++c) red[tid][c] += red[tid + off][c];
        }
        __syncthreads();
    }
    if (tid < NCLASS) atomicAdd(out + b * NCLASS + tid, red[0][tid]);
}

// ===========================================================================
extern "C" void kernel_launch(void* const* d_in, const int* in_sizes, int n_in,
                              void* d_out, int out_size, void* d_ws, size_t ws_size,
                              hipStream_t stream) {
    const int*   data = (const int*)d_in[0];
    const float* emb  = (const float*)d_in[1];
    const float* fw1  = (const float*)d_in[2];
    const float* fb1  = (const float*)d_in[3];
    const float* fw2  = (const float*)d_in[4];
    const float* fb2  = (const float*)d_in[5];
    const float* Wf   = (const float*)d_in[6];
    const float* bf   = (const float*)d_in[7];
    float* out = (float*)d_out;

    float* X  = (float*)d_ws;                       // 1048576
    float* VA = X + NB * NVEC * NDIM;               // 1048576
    float* VB = VA + NB * NVEC * NDIM;              // 1048576
    float* H  = VB + NB * NVEC * NDIM;              // 16777216 (fallback only)
    float* Upart = H + (size_t)NW * NB * NVEC * NHID;  // 1056768 (fallback only)
    // coop-only buffers alias the (coop-unused) H region:
    float* UA = H;
    float* UB = H + NB * USIZE;

    void* args[] = {(void*)&data, (void*)&emb, (void*)&fw1, (void*)&fb1,
                    (void*)&fw2, (void*)&fb2, (void*)&Wf, (void*)&bf,
                    (void*)&out, (void*)&X, (void*)&VA, (void*)&VB,
                    (void*)&UA, (void*)&UB};
    hipError_t err = hipLaunchCooperativeKernel((void*)k_mega, dim3(NBLK),
                                                dim3(256), args, 0, stream);
    if (err != hipSuccess) {
        (void)hipGetLastError();   // clear error state; run fallback path
        k_embed<<<dim3((NB * NVEC * NDIM) / 256), 256, 0, stream>>>(data, emb, X);
        k_H<<<dim3(NVEC / 64, NB, NW), 256, 0, stream>>>(X, fw1, fb1, H);
        const float* Vcur = X;
        float* Vnext = VA;
        for (int i = NW - 1; i >= 0; --i) {
            k_U<<<dim3(MS_FB, NB), 256, 0, stream>>>(Vcur, fw2 + (size_t)i * NHID * NVEC,
                                                     fb2 + (size_t)i * NVEC, Upart);
            k_apply<<<dim3(NVEC / 64, NB), 256, 0, stream>>>(
                H + (size_t)i * NB * NVEC * NHID, Upart, Vnext);
            Vcur = Vnext;
            Vnext = (Vnext == VA) ? VB : VA;
        }
        k_bias_out<<<1, 256, 0, stream>>>(bf, out);
        k_final<<<dim3(NB, 32), 256, 0, stream>>>(Vcur, Wf, out);
    }
}

// Round 6
// 234.107 us; speedup vs baseline: 4.5856x; 4.5856x over previous
//
#include <hip/hip_runtime.h>
#include <hip/hip_bf16.h>

#define NB 16
#define NVEC 2048
#define NDIM 32
#define NW 4
#define NHID 128
#define NCLASS 10
#define MS 16              // m-splits for k_U
#define USIZE (129 * 32)   // 4128: U rows 0..127 = fw2@V, row 128 = fb2^T@V

// tanh-approx GELU; validated absmax 0.0 vs ref in R5 (bf16-rounded compare).
__device__ __forceinline__ float gelu_fast(float x) {
    float t = 1.5957691216057308f * x * (1.0f + 0.044715f * x * x);
    return x / (1.0f + __expf(-t));
}

// ---------------------------------------------------------------------------
// Embed gather + out=bias init (for k_final's atomics). 4096 blocks.
__global__ __launch_bounds__(256) void k_embed(const int* __restrict__ data,
                                               const float* __restrict__ emb,
                                               const float* __restrict__ bf,
                                               float* __restrict__ X,
                                               float* __restrict__ out) {
    int gid = blockIdx.x * 256 + threadIdx.x;   // NB*NVEC*NDIM = 1048576
    int row = gid >> 5, d = gid & 31;
    X[gid] = emb[data[row] * NDIM + d];
    if (blockIdx.x == 0 && threadIdx.x < NB * NCLASS)
        out[threadIdx.x] = bf[threadIdx.x % NCLASS];
}

// ---------------------------------------------------------------------------
// Split-m partial U: grid (MS, NB). Block: 128 m's for one b. (R3-proven.)
__global__ __launch_bounds__(256) void k_U(const float* __restrict__ V,
                                           const float* __restrict__ fw2,
                                           const float* __restrict__ fb2,
                                           float* __restrict__ Upart) {
    __shared__ float Vs[128 * 32];       // [mm][d], 16 KB
    __shared__ float fw2s[128][33];      // [k][mm] pad 1
    __shared__ float cred[4][33];
    int ms = blockIdx.x, b = blockIdx.y;
    int tid = threadIdx.x;
    int m0 = ms * 128;
    const float* Vb = V + (b * NVEC + m0) * NDIM;
#pragma unroll
    for (int j = 0; j < 4; ++j) {
        int i4 = tid + j * 256;
        ((float4*)Vs)[i4] = ((const float4*)Vb)[i4];
    }
    int k1 = tid & 63, k2 = k1 + 64, d0 = (tid >> 6) * 8;
    float acc1[8], acc2[8];
#pragma unroll
    for (int j = 0; j < 8; ++j) { acc1[j] = 0.f; acc2[j] = 0.f; }
    for (int s = 0; s < 4; ++s) {
        __syncthreads();
        int moff = m0 + s * 32;
#pragma unroll
        for (int j = 0; j < 16; ++j) {
            int i = tid + j * 256;
            int kk = i >> 5, mm = i & 31;
            fw2s[kk][mm] = fw2[kk * NVEC + moff + mm];
        }
        __syncthreads();
#pragma unroll 8
        for (int mm = 0; mm < 32; ++mm) {
            float w1v = fw2s[k1][mm];
            float w2v = fw2s[k2][mm];
            const float* vrow = &Vs[(s * 32 + mm) * 32 + d0];
            float4 va = *(const float4*)vrow;
            float4 vb4 = *(const float4*)(vrow + 4);
            float vv[8] = {va.x, va.y, va.z, va.w, vb4.x, vb4.y, vb4.z, vb4.w};
#pragma unroll
            for (int j = 0; j < 8; ++j) {
                acc1[j] += w1v * vv[j];
                acc2[j] += w2v * vv[j];
            }
        }
    }
    float* Up = Upart + ((size_t)ms * NB + b) * USIZE;
    *(float4*)&Up[k1 * 32 + d0]     = make_float4(acc1[0], acc1[1], acc1[2], acc1[3]);
    *(float4*)&Up[k1 * 32 + d0 + 4] = make_float4(acc1[4], acc1[5], acc1[6], acc1[7]);
    *(float4*)&Up[k2 * 32 + d0]     = make_float4(acc2[0], acc2[1], acc2[2], acc2[3]);
    *(float4*)&Up[k2 * 32 + d0 + 4] = make_float4(acc2[4], acc2[5], acc2[6], acc2[7]);
    if (tid < 128) {
        int d = tid & 31, seg = tid >> 5;
        float ca = 0.f;
#pragma unroll 8
        for (int mm = seg * 32; mm < seg * 32 + 32; ++mm)
            ca += fb2[m0 + mm] * Vs[mm * 32 + d];
        cred[seg][d] = ca;
    }
    __syncthreads();
    if (tid < 32)
        Up[128 * 32 + tid] = cred[0][tid] + cred[1][tid] + cred[2][tid] + cred[3][tid];
}

// ---------------------------------------------------------------------------
// Fused h+apply: grid (NVEC/64, NB). Per block: reduce U partials (16 KB),
// stage fw1 (16 KB), then 2 subtiles of 32 rows:
//   h = gelu_fast(X@fw1 + fb1) in LDS;  V_new = h @ U + U[128,:].
// LDS 13472 floats = 52.6 KiB -> 3 blocks/CU.
__global__ __launch_bounds__(256) void k_applyF(const float* __restrict__ X,
                                                const float* __restrict__ fw1l,
                                                const float* __restrict__ fb1l,
                                                const float* __restrict__ Upart,
                                                float* __restrict__ Vout) {
    __shared__ float Us[USIZE];          // 4128
    __shared__ float w1s[NDIM * NHID];   // 4096, [d][k]
    __shared__ float xs[32][33];         // 1056, padded: conflict-free row reads
    __shared__ float hs[32 * 132];       // 4224, [r][k]
    int ng = blockIdx.x, b = blockIdx.y;
    int tid = threadIdx.x;

    {   // reduce the 16 m-split partials of U (float4, from L2)
        for (int i4 = tid; i4 < USIZE / 4; i4 += 256) {
            float4 s = ((const float4*)(Upart + (size_t)b * USIZE))[i4];
#pragma unroll
            for (int ms = 1; ms < MS; ++ms) {
                float4 v = ((const float4*)(Upart + ((size_t)ms * NB + b) * USIZE))[i4];
                s.x += v.x; s.y += v.y; s.z += v.z; s.w += v.w;
            }
            ((float4*)Us)[i4] = s;
        }
    }
#pragma unroll
    for (int j = 0; j < 4; ++j)
        ((float4*)w1s)[tid + j * 256] = ((const float4*)fw1l)[tid + j * 256];

    int kg = tid & 15, rg = tid >> 4;    // h-phase: 2 rows x 8 k
    int k0 = kg * 8, r0 = rg * 2;
    int d0 = (tid & 7) * 4, ra = tid >> 3;  // apply: 1 row x 4 d

#pragma unroll
    for (int t = 0; t < 2; ++t) {
        int n0 = ng * 64 + t * 32;
        {   // stage X rows (padded layout; scalar writes, coalesced read)
            float4 v = ((const float4*)(X + (b * NVEC + n0) * NDIM))[tid];
            int r = tid >> 3, c4 = (tid & 7) * 4;
            xs[r][c4] = v.x; xs[r][c4 + 1] = v.y;
            xs[r][c4 + 2] = v.z; xs[r][c4 + 3] = v.w;
        }
        __syncthreads();                 // covers Us/w1s (t=0) + xs

        {   // h: 2 rows x 8 k per thread
            float acc[2][8];
#pragma unroll
            for (int j = 0; j < 8; ++j) {
                float bv = fb1l[k0 + j];
                acc[0][j] = bv; acc[1][j] = bv;
            }
#pragma unroll 8
            for (int d = 0; d < NDIM; ++d) {
                float x0 = xs[r0][d], x1 = xs[r0 + 1][d];
                float4 wa = *(const float4*)&w1s[d * NHID + k0];
                float4 wb = *(const float4*)&w1s[d * NHID + k0 + 4];
                float wk[8] = {wa.x, wa.y, wa.z, wa.w, wb.x, wb.y, wb.z, wb.w};
#pragma unroll
                for (int j = 0; j < 8; ++j) {
                    acc[0][j] += x0 * wk[j];
                    acc[1][j] += x1 * wk[j];
                }
            }
#pragma unroll
            for (int r = 0; r < 2; ++r) {
                float4 o0, o1;
                o0.x = gelu_fast(acc[r][0]); o0.y = gelu_fast(acc[r][1]);
                o0.z = gelu_fast(acc[r][2]); o0.w = gelu_fast(acc[r][3]);
                o1.x = gelu_fast(acc[r][4]); o1.y = gelu_fast(acc[r][5]);
                o1.z = gelu_fast(acc[r][6]); o1.w = gelu_fast(acc[r][7]);
                *(float4*)&hs[(r0 + r) * 132 + k0] = o0;
                *(float4*)&hs[(r0 + r) * 132 + k0 + 4] = o1;
            }
        }
        __syncthreads();

        {   // apply: 1 row x 4 d over K=128
            float4 a = *(const float4*)&Us[NHID * 32 + d0];
#pragma unroll 8
            for (int k = 0; k < NHID; k += 4) {
                float4 h0 = *(const float4*)&hs[ra * 132 + k];
                float4 u0 = *(const float4*)&Us[(k + 0) * 32 + d0];
                float4 u1 = *(const float4*)&Us[(k + 1) * 32 + d0];
                float4 u2 = *(const float4*)&Us[(k + 2) * 32 + d0];
                float4 u3 = *(const float4*)&Us[(k + 3) * 32 + d0];
                a.x += h0.x * u0.x + h0.y * u1.x + h0.z * u2.x + h0.w * u3.x;
                a.y += h0.x * u0.y + h0.y * u1.y + h0.z * u2.y + h0.w * u3.y;
                a.z += h0.x * u0.z + h0.y * u1.z + h0.z * u2.z + h0.w * u3.z;
                a.w += h0.x * u0.w + h0.y * u1.w + h0.z * u2.w + h0.w * u3.w;
            }
            *(float4*)&Vout[(b * NVEC + n0 + ra) * NDIM + d0] = a;
        }
        __syncthreads();                 // xs/hs reused by next subtile
    }
}

// ---------------------------------------------------------------------------
// out[b,c] += sum_j V[b,j] * Wf[j,c];  grid (NB, 32). out pre-set to bias.
__global__ __launch_bounds__(256) void k_final(const float* __restrict__ V,
                                               const float* __restrict__ Wf,
                                               float* __restrict__ out) {
    int b = blockIdx.x, chunk = blockIdx.y;
    int tid = threadIdx.x;
    float acc[NCLASS];
#pragma unroll
    for (int c = 0; c < NCLASS; ++c) acc[c] = 0.f;
    const float* Vb = V + b * (NVEC * NDIM);
    int j0 = chunk * 2048;
    for (int j = j0 + tid; j < j0 + 2048; j += 256) {
        float v = Vb[j];
        const float* wr = Wf + (size_t)j * NCLASS;
#pragma unroll
        for (int c = 0; c < NCLASS; ++c) acc[c] += v * wr[c];
    }
    __shared__ float red[256][NCLASS];
#pragma unroll
    for (int c = 0; c < NCLASS; ++c) red[tid][c] = acc[c];
    __syncthreads();
    for (int off = 128; off >= 1; off >>= 1) {
        if (tid < off) {
#pragma unroll
            for (int c = 0; c < NCLASS; ++c) red[tid][c] += red[tid + off][c];
        }
        __syncthreads();
    }
    if (tid < NCLASS) atomicAdd(out + b * NCLASS + tid, red[0][tid]);
}

// ---------------------------------------------------------------------------
extern "C" void kernel_launch(void* const* d_in, const int* in_sizes, int n_in,
                              void* d_out, int out_size, void* d_ws, size_t ws_size,
                              hipStream_t stream) {
    const int*   data = (const int*)d_in[0];
    const float* emb  = (const float*)d_in[1];
    const float* fw1  = (const float*)d_in[2];
    const float* fb1  = (const float*)d_in[3];
    const float* fw2  = (const float*)d_in[4];
    const float* fb2  = (const float*)d_in[5];
    const float* Wf   = (const float*)d_in[6];
    const float* bf   = (const float*)d_in[7];
    float* out = (float*)d_out;

    float* X     = (float*)d_ws;                    // 1048576
    float* VA    = X + NB * NVEC * NDIM;            // 1048576
    float* VB    = VA + NB * NVEC * NDIM;           // 1048576
    float* Upart = VB + NB * NVEC * NDIM;           // 16*16*4128 = 1056768

    k_embed<<<dim3((NB * NVEC * NDIM) / 256), 256, 0, stream>>>(data, emb, bf, X, out);

    const float* Vcur = X;
    float* Vnext = VA;
    for (int i = NW - 1; i >= 0; --i) {
        k_U<<<dim3(MS, NB), 256, 0, stream>>>(Vcur, fw2 + (size_t)i * NHID * NVEC,
                                              fb2 + (size_t)i * NVEC, Upart);
        k_applyF<<<dim3(NVEC / 64, NB), 256, 0, stream>>>(
            X, fw1 + (size_t)i * NDIM * NHID, fb1 + (size_t)i * NHID, Upart, Vnext);
        Vcur = Vnext;
        Vnext = (Vnext == VA) ? VB : VA;
    }

    k_final<<<dim3(NB, 32), 256, 0, stream>>>(Vcur, Wf, out);
}